// Round 1
// baseline (11535.249 us; speedup 1.0000x reference)
//
#include <hip/hip_runtime.h>
#include <math.h>

// Problem constants (B,S,LAT,E,H,NB) = (2,1024,64,1024,8,4); HD=64, ROT=32.
#define B_ 2
#define S_ 1024
#define E_ 1024

// ---------------------------------------------------------------------------
// Generic tiled fp32 GEMM: C[M,N] = A[M,K] @ W[K,N] (+bias) with epilogues.
// MODE 0: plain.  MODE 1: snake(z) = z + sin(alpha[n]*z)^2/(beta[n]+1e-9).
// MODE 2: C = z * sigmoid(1 - gate[b(m), n]) + resid[m,n]   (b(m) = m / S_)
// Requires M%64==0, N%64==0, K%16==0 (true for all shapes here).
// ---------------------------------------------------------------------------
constexpr int BM = 64, BN = 64, BK = 16;

template <int MODE>
__global__ __launch_bounds__(256) void gemm_k(
    const float* __restrict__ A, const float* __restrict__ W,
    const float* __restrict__ bias, float* __restrict__ C,
    int M, int N, int K,
    const float* __restrict__ e1, const float* __restrict__ e2,
    const float* __restrict__ resid, int estride)
{
    __shared__ float As[BK][BM + 1];
    __shared__ float Ws[BK][BN + 1];
    const int tid = threadIdx.x;
    const int bn = blockIdx.x * BN;
    const int bm = blockIdx.y * BM;
    const int tx = tid & 15, ty = tid >> 4;

    const int am = tid >> 2;          // 0..63  (A tile row)
    const int ak = (tid & 3) * 4;     // 0,4,8,12 (A tile k, float4)
    const int wk = tid >> 4;          // 0..15  (W tile k)
    const int wn = (tid & 15) * 4;    // 0..60  (W tile col, float4)

    float acc[4][4] = {};

    for (int k0 = 0; k0 < K; k0 += BK) {
        float4 a4 = *(const float4*)(A + (size_t)(bm + am) * K + k0 + ak);
        float4 w4 = *(const float4*)(W + (size_t)(k0 + wk) * N + bn + wn);
        As[ak + 0][am] = a4.x; As[ak + 1][am] = a4.y;
        As[ak + 2][am] = a4.z; As[ak + 3][am] = a4.w;
        Ws[wk][wn + 0] = w4.x; Ws[wk][wn + 1] = w4.y;
        Ws[wk][wn + 2] = w4.z; Ws[wk][wn + 3] = w4.w;
        __syncthreads();
#pragma unroll
        for (int kk = 0; kk < BK; ++kk) {
            float a[4], b[4];
#pragma unroll
            for (int r = 0; r < 4; ++r) a[r] = As[kk][ty * 4 + r];
#pragma unroll
            for (int c = 0; c < 4; ++c) b[c] = Ws[kk][tx * 4 + c];
#pragma unroll
            for (int r = 0; r < 4; ++r)
#pragma unroll
                for (int c = 0; c < 4; ++c) acc[r][c] += a[r] * b[c];
        }
        __syncthreads();
    }

#pragma unroll
    for (int r = 0; r < 4; ++r) {
        const int m = bm + ty * 4 + r;
#pragma unroll
        for (int c = 0; c < 4; ++c) {
            const int n = bn + tx * 4 + c;
            float z = acc[r][c];
            if (bias) z += bias[n];
            if (MODE == 1) {
                float s = sinf(e1[n] * z);
                z = z + s * s / (e2[n] + 1e-9f);
            } else if (MODE == 2) {
                const int bb = m >> 10;  // m / S_
                float g = e1[(size_t)bb * estride + n];
                float gate = 1.f / (1.f + expf(-(1.f - g)));
                z = z * gate + resid[(size_t)m * N + n];
            }
            C[(size_t)m * N + n] = z;
        }
    }
}

// ---------------------------------------------------------------------------
// LayerNorm (+ optional affine) followed by adaLN modulation:
//   out = LN(x)[*w+b] * (1 + sc[b, e]) + sh[b, e]
// One block per row (E_=1024, 256 threads, 4 elems/thread).
// ---------------------------------------------------------------------------
__global__ __launch_bounds__(256) void ln_mod_k(
    const float* __restrict__ x, const float* __restrict__ w,
    const float* __restrict__ b, const float* __restrict__ scp,
    const float* __restrict__ shp, int bstride, float eps,
    float* __restrict__ out)
{
    const int row = blockIdx.x;
    const int tid = threadIdx.x;
    const int bb = row >> 10;  // row / S_
    const float* xr = x + (size_t)row * E_;
    float4 v = ((const float4*)xr)[tid];
    float xv[4] = {v.x, v.y, v.z, v.w};
    float s = xv[0] + xv[1] + xv[2] + xv[3];
    float sq = xv[0] * xv[0] + xv[1] * xv[1] + xv[2] * xv[2] + xv[3] * xv[3];
    __shared__ float r1[256], r2[256];
    r1[tid] = s; r2[tid] = sq;
    __syncthreads();
    for (int o = 128; o > 0; o >>= 1) {
        if (tid < o) { r1[tid] += r1[tid + o]; r2[tid] += r2[tid + o]; }
        __syncthreads();
    }
    const float mean = r1[0] * (1.f / E_);
    const float var = r2[0] * (1.f / E_) - mean * mean;
    const float rs = rsqrtf(var + eps);
#pragma unroll
    for (int l = 0; l < 4; ++l) {
        const int e = tid * 4 + l;
        float y = (xv[l] - mean) * rs;
        if (w) y = y * w[e] + b[e];
        y = y * (1.f + scp[(size_t)bb * bstride + e]) + shp[(size_t)bb * bstride + e];
        out[(size_t)row * E_ + e] = y;
    }
}

// ---------------------------------------------------------------------------
// Rotary on q and k (first ROT=32 dims of each of the 2H=16 heads), in place.
// One thread per (b, s, head16, pair j<16); handles both q and k.
// ---------------------------------------------------------------------------
__global__ __launch_bounds__(256) void rotary_k(float* __restrict__ qkv)
{
    const int idx = blockIdx.x * 256 + threadIdx.x;  // < 2^19
    const int j = idx & 15;
    const int hh = (idx >> 4) & 15;
    const int si = (idx >> 8) & 1023;
    const int b = idx >> 18;
    const float ang = (float)si * powf(10000.f, -(float)j * (1.f / 16.f));
    float sn, cs;
    sincosf(ang, &sn, &cs);
    float* base = qkv + ((size_t)(b * S_ + si)) * (3 * E_) + hh * 64 + 2 * j;
    float x1 = base[0], x2 = base[1];
    base[0] = x1 * cs - x2 * sn;
    base[1] = x2 * cs + x1 * sn;
    float* kb = base + E_;
    x1 = kb[0]; x2 = kb[1];
    kb[0] = x1 * cs - x2 * sn;
    kb[1] = x2 * cs + x1 * sn;
}

// ---------------------------------------------------------------------------
// lambda[i] = exp(sum(lq1[i]*lk1[i])) - exp(sum(lq2[i]*lk2[i])) + lam_init[i]
// One block, wave w handles block w (wave64 shuffle reduce).
// ---------------------------------------------------------------------------
__global__ __launch_bounds__(256) void lam_k(
    const float* __restrict__ lq1, const float* __restrict__ lk1,
    const float* __restrict__ lq2, const float* __restrict__ lk2,
    float* __restrict__ lamout, float li0, float li1, float li2, float li3)
{
    const int w = threadIdx.x >> 6, lane = threadIdx.x & 63;
    float s1 = lq1[w * 64 + lane] * lk1[w * 64 + lane];
    float s2 = lq2[w * 64 + lane] * lk2[w * 64 + lane];
    for (int o = 32; o > 0; o >>= 1) {
        s1 += __shfl_down(s1, o);
        s2 += __shfl_down(s2, o);
    }
    if (lane == 0) {
        float li = (w == 0) ? li0 : (w == 1) ? li1 : (w == 2) ? li2 : li3;
        lamout[w] = expf(s1) - expf(s2) + li;
    }
}

// ---------------------------------------------------------------------------
// Tiny GEMM for modulation: out[b,n] = bias[n] + sum_k emb[b,k]*W[k,n].
// Requires (B_*N) % 256 == 0 and N % 256 == 0.
// ---------------------------------------------------------------------------
__global__ __launch_bounds__(256) void small_gemm_k(
    const float* __restrict__ emb, const float* __restrict__ W,
    const float* __restrict__ bias, float* __restrict__ out, int N)
{
    const int idx = blockIdx.x * 256 + threadIdx.x;
    const int b = idx / N, n = idx % N;
    const float* er = emb + (size_t)b * E_;
    float acc = bias[n];
#pragma unroll 8
    for (int k = 0; k < E_; ++k) acc += er[k] * W[(size_t)k * N + n];
    out[idx] = acc;
}

// ---------------------------------------------------------------------------
// Fused differential attention for one (b, h, query i):
//  - scores for component heads 2h (q1·k1) and 2h+1 (q2·k2), causal j<=i
//  - two softmaxes (LDS), PV with shared v, A1 - lam*A2, RMSNorm(aln), *(1-li)
// Writes out[b, i, h*128 + e].
// ---------------------------------------------------------------------------
__global__ __launch_bounds__(256) void attn_k(
    const float* __restrict__ qkv, const float* __restrict__ lamptr,
    const float* __restrict__ alnw, const float* __restrict__ alnb,
    float* __restrict__ out, float omli)
{
    const int i = blockIdx.x, h = blockIdx.y, b = blockIdx.z;
    const int tid = threadIdx.x;
    __shared__ float sq[128];
    __shared__ float p1[S_], p2[S_];
    __shared__ float red[512];
    __shared__ float dval[128];

    const size_t rowQ = ((size_t)b * S_ + i) * (3 * E_);
    if (tid < 128) sq[tid] = qkv[rowQ + h * 128 + tid];
    __syncthreads();

    // scores + local max
    float lm1 = -3e38f, lm2 = -3e38f;
    for (int j = tid; j <= i; j += 256) {
        const float* kr = qkv + ((size_t)b * S_ + j) * (3 * E_) + E_ + h * 128;
        float d1 = 0.f, d2 = 0.f;
#pragma unroll
        for (int d = 0; d < 64; d += 4) {
            float4 k1 = *(const float4*)(kr + d);
            float4 k2 = *(const float4*)(kr + 64 + d);
            float4 q1 = *(const float4*)(sq + d);
            float4 q2 = *(const float4*)(sq + 64 + d);
            d1 += q1.x * k1.x + q1.y * k1.y + q1.z * k1.z + q1.w * k1.w;
            d2 += q2.x * k2.x + q2.y * k2.y + q2.z * k2.z + q2.w * k2.w;
        }
        d1 *= 0.125f; d2 *= 0.125f;
        p1[j] = d1; p2[j] = d2;
        lm1 = fmaxf(lm1, d1); lm2 = fmaxf(lm2, d2);
    }
    red[tid] = lm1; red[256 + tid] = lm2;
    __syncthreads();
    for (int o = 128; o > 0; o >>= 1) {
        if (tid < o) {
            red[tid] = fmaxf(red[tid], red[tid + o]);
            red[256 + tid] = fmaxf(red[256 + tid], red[256 + tid + o]);
        }
        __syncthreads();
    }
    const float m1 = red[0], m2 = red[256];
    __syncthreads();

    // exp + sum
    float s1 = 0.f, s2 = 0.f;
    for (int j = tid; j <= i; j += 256) {
        float e1 = expf(p1[j] - m1);
        float e2 = expf(p2[j] - m2);
        p1[j] = e1; p2[j] = e2;
        s1 += e1; s2 += e2;
    }
    red[tid] = s1; red[256 + tid] = s2;
    __syncthreads();
    for (int o = 128; o > 0; o >>= 1) {
        if (tid < o) {
            red[tid] += red[tid + o];
            red[256 + tid] += red[256 + tid + o];
        }
        __syncthreads();
    }
    const float l1 = red[0], l2 = red[256];
    __syncthreads();

    // PV: e = tid&127, two j-halves
    const int e = tid & 127, half = tid >> 7;
    float a1 = 0.f, a2 = 0.f;
    for (int j = half; j <= i; j += 2) {
        float vv = qkv[((size_t)b * S_ + j) * (3 * E_) + 2 * E_ + h * 128 + e];
        a1 += p1[j] * vv;
        a2 += p2[j] * vv;
    }
    red[tid] = a1; red[256 + tid] = a2;
    __syncthreads();

    const float lam = *lamptr;
    if (tid < 128) {
        float A1 = (red[tid] + red[tid + 128]) / l1;
        float A2 = (red[256 + tid] + red[256 + tid + 128]) / l2;
        dval[tid] = A1 - lam * A2;
    }
    __syncthreads();
    red[tid] = (tid < 128) ? dval[tid] * dval[tid] : 0.f;
    __syncthreads();
    for (int o = 128; o > 0; o >>= 1) {
        if (tid < o) red[tid] += red[tid + o];
        __syncthreads();
    }
    const float rs = rsqrtf(red[0] * (1.f / 128.f) + 1e-8f);
    if (tid < 128) {
        float o = (dval[tid] * rs * alnw[tid] + alnb[tid]) * omli;
        out[((size_t)b * S_ + i) * E_ + h * 128 + tid] = o;
    }
}

// ---------------------------------------------------------------------------
extern "C" void kernel_launch(void* const* d_in, const int* in_sizes, int n_in,
                              void* d_out, int out_size, void* d_ws, size_t ws_size,
                              hipStream_t stream)
{
    const float* x      = (const float*)d_in[0];
    const float* emb    = (const float*)d_in[1];
    const float* l2e_w1 = (const float*)d_in[2];
    const float* l2e_b1 = (const float*)d_in[3];
    const float* l2e_al = (const float*)d_in[4];
    const float* l2e_be = (const float*)d_in[5];
    const float* l2e_w2 = (const float*)d_in[6];
    const float* l2e_b2 = (const float*)d_in[7];
    const float* ln1_w  = (const float*)d_in[8];
    const float* ln1_b  = (const float*)d_in[9];
    const float* ln2_w  = (const float*)d_in[10];
    const float* ln2_b  = (const float*)d_in[11];
    const float* qkv_w  = (const float*)d_in[12];
    const float* out_w  = (const float*)d_in[13];
    const float* lq1    = (const float*)d_in[14];
    const float* lk1    = (const float*)d_in[15];
    const float* lq2    = (const float*)d_in[16];
    const float* lk2    = (const float*)d_in[17];
    const float* aln_w  = (const float*)d_in[18];
    const float* aln_b  = (const float*)d_in[19];
    const float* ada_w  = (const float*)d_in[20];
    const float* ada_b  = (const float*)d_in[21];
    const float* ff_w1  = (const float*)d_in[22];
    const float* ff_b1  = (const float*)d_in[23];
    const float* ff_al  = (const float*)d_in[24];
    const float* ff_be  = (const float*)d_in[25];
    const float* ff_w2  = (const float*)d_in[26];
    const float* ff_b2  = (const float*)d_in[27];
    const float* adaf_w = (const float*)d_in[28];
    const float* adaf_b = (const float*)d_in[29];
    const float* fin_w  = (const float*)d_in[30];
    const float* fin_b  = (const float*)d_in[31];
    float* outp = (float*)d_out;

    const int M = B_ * S_;               // 2048
    const size_t MN = (size_t)M * E_;    // 2,097,152 floats
    float* ws    = (float*)d_ws;
    float* hbuf  = ws;                   // MN
    float* tbuf  = ws + MN;              // MN
    float* big   = ws + 2 * MN;          // 4*MN (qkv uses 3*MN; ff uses 4*MN)
    float* abuf  = ws + 6 * MN;          // MN  (attention output)
    float* mods  = abuf + MN;            // 4 * B_ * 6E = 49152
    float* adafm = mods + 4 * B_ * 6 * E_;  // B_*2E = 4096
    float* lamb  = adafm + B_ * 2 * E_;     // 4
    // total ~ 7*MN + 53k floats ~= 59 MB

    double li[4];
    for (int i = 0; i < 4; ++i) li[i] = 0.8 - 0.6 * exp(-0.3 * (i + 1));

    lam_k<<<1, 256, 0, stream>>>(lq1, lk1, lq2, lk2, lamb,
                                 (float)li[0], (float)li[1], (float)li[2], (float)li[3]);
    for (int i = 0; i < 4; ++i)
        small_gemm_k<<<(B_ * 6 * E_) / 256, 256, 0, stream>>>(
            emb, ada_w + (size_t)i * E_ * 6 * E_, ada_b + (size_t)i * 6 * E_,
            mods + (size_t)i * B_ * 6 * E_, 6 * E_);
    small_gemm_k<<<(B_ * 2 * E_) / 256, 256, 0, stream>>>(emb, adaf_w, adaf_b, adafm, 2 * E_);

    // l2e: t = snake(x @ w1 + b1); h = t @ w2 + b2
    gemm_k<1><<<dim3(E_ / 64, M / 64), 256, 0, stream>>>(
        x, l2e_w1, l2e_b1, tbuf, M, E_, 64, l2e_al, l2e_be, nullptr, 0);
    gemm_k<0><<<dim3(E_ / 64, M / 64), 256, 0, stream>>>(
        tbuf, l2e_w2, l2e_b2, hbuf, M, E_, E_, nullptr, nullptr, nullptr, 0);

    for (int i = 0; i < 4; ++i) {
        const float* mi = mods + (size_t)i * B_ * 6 * E_;
        const float omli = 1.f - (float)li[i];

        ln_mod_k<<<M, 256, 0, stream>>>(hbuf, ln1_w + i * E_, ln1_b + i * E_,
                                        mi, mi + E_, 6 * E_, 1e-5f, tbuf);
        gemm_k<0><<<dim3(3 * E_ / 64, M / 64), 256, 0, stream>>>(
            tbuf, qkv_w + (size_t)i * E_ * 3 * E_, nullptr, big, M, 3 * E_, E_,
            nullptr, nullptr, nullptr, 0);
        rotary_k<<<(B_ * S_ * 16 * 16) / 256, 256, 0, stream>>>(big);
        attn_k<<<dim3(S_, 8, B_), 256, 0, stream>>>(
            big, lamb + i, aln_w + i * 128, aln_b + i * 128, abuf, omli);
        gemm_k<2><<<dim3(E_ / 64, M / 64), 256, 0, stream>>>(
            abuf, out_w + (size_t)i * E_ * E_, nullptr, hbuf, M, E_, E_,
            mi + 4 * E_, nullptr, hbuf, 6 * E_);

        ln_mod_k<<<M, 256, 0, stream>>>(hbuf, ln2_w + i * E_, ln2_b + i * E_,
                                        mi + 2 * E_, mi + 3 * E_, 6 * E_, 1e-5f, tbuf);
        gemm_k<1><<<dim3(4 * E_ / 64, M / 64), 256, 0, stream>>>(
            tbuf, ff_w1 + (size_t)i * E_ * 4 * E_, ff_b1 + i * 4 * E_, big,
            M, 4 * E_, E_, ff_al + i * 4 * E_, ff_be + i * 4 * E_, nullptr, 0);
        gemm_k<2><<<dim3(E_ / 64, M / 64), 256, 0, stream>>>(
            big, ff_w2 + (size_t)i * 4 * E_ * E_, ff_b2 + i * E_, hbuf,
            M, E_, 4 * E_, mi + 5 * E_, nullptr, hbuf, 6 * E_);
    }

    // final: t = ln_na(h)*(1+sc)+sh ; out = t @ fin_w + fin_b
    ln_mod_k<<<M, 256, 0, stream>>>(hbuf, nullptr, nullptr, adafm, adafm + E_,
                                    2 * E_, 1e-6f, tbuf);
    gemm_k<0><<<dim3(1, M / 64), 256, 0, stream>>>(
        tbuf, fin_w, fin_b, outp, M, 64, E_, nullptr, nullptr, nullptr, 0);
}

// Round 2
// 5744.845 us; speedup vs baseline: 2.0079x; 2.0079x over previous
//
#include <hip/hip_runtime.h>
#include <math.h>

// Problem constants (B,S,LAT,E,H,NB) = (2,1024,64,1024,8,4); HD=64, ROT=32.
#define B_ 2
#define S_ 1024
#define E_ 1024

typedef __attribute__((ext_vector_type(8))) short bf16x8;
typedef __attribute__((ext_vector_type(4))) float f32x4;
typedef __attribute__((ext_vector_type(4))) short sh4;

__device__ __forceinline__ short f2bf(float x) {
    unsigned u = __float_as_uint(x);
    unsigned r = (u + 0x7FFFu + ((u >> 16) & 1u)) >> 16;
    return (short)r;
}

// ---------------------------------------------------------------------------
// Generic tiled fp32 GEMM: C[M,N] = A[M,K] @ W[K,N] (+bias) with epilogues.
// MODE 0: plain.  MODE 1: snake.  MODE 2: gate*sigmoid + residual.
// ---------------------------------------------------------------------------
constexpr int BM = 64, BN = 64, BK = 16;

template <int MODE>
__global__ __launch_bounds__(256) void gemm_k(
    const float* __restrict__ A, const float* __restrict__ W,
    const float* __restrict__ bias, float* __restrict__ C,
    int M, int N, int K,
    const float* __restrict__ e1, const float* __restrict__ e2,
    const float* __restrict__ resid, int estride)
{
    __shared__ float As[BK][BM + 1];
    __shared__ float Ws[BK][BN + 1];
    const int tid = threadIdx.x;
    const int bn = blockIdx.x * BN;
    const int bm = blockIdx.y * BM;
    const int tx = tid & 15, ty = tid >> 4;

    const int am = tid >> 2;
    const int ak = (tid & 3) * 4;
    const int wk = tid >> 4;
    const int wn = (tid & 15) * 4;

    float acc[4][4] = {};

    for (int k0 = 0; k0 < K; k0 += BK) {
        float4 a4 = *(const float4*)(A + (size_t)(bm + am) * K + k0 + ak);
        float4 w4 = *(const float4*)(W + (size_t)(k0 + wk) * N + bn + wn);
        As[ak + 0][am] = a4.x; As[ak + 1][am] = a4.y;
        As[ak + 2][am] = a4.z; As[ak + 3][am] = a4.w;
        Ws[wk][wn + 0] = w4.x; Ws[wk][wn + 1] = w4.y;
        Ws[wk][wn + 2] = w4.z; Ws[wk][wn + 3] = w4.w;
        __syncthreads();
#pragma unroll
        for (int kk = 0; kk < BK; ++kk) {
            float a[4], b[4];
#pragma unroll
            for (int r = 0; r < 4; ++r) a[r] = As[kk][ty * 4 + r];
#pragma unroll
            for (int c = 0; c < 4; ++c) b[c] = Ws[kk][tx * 4 + c];
#pragma unroll
            for (int r = 0; r < 4; ++r)
#pragma unroll
                for (int c = 0; c < 4; ++c) acc[r][c] += a[r] * b[c];
        }
        __syncthreads();
    }

#pragma unroll
    for (int r = 0; r < 4; ++r) {
        const int m = bm + ty * 4 + r;
#pragma unroll
        for (int c = 0; c < 4; ++c) {
            const int n = bn + tx * 4 + c;
            float z = acc[r][c];
            if (bias) z += bias[n];
            if (MODE == 1) {
                float s = sinf(e1[n] * z);
                z = z + s * s / (e2[n] + 1e-9f);
            } else if (MODE == 2) {
                const int bb = m >> 10;
                float g = e1[(size_t)bb * estride + n];
                float gate = 1.f / (1.f + expf(-(1.f - g)));
                z = z * gate + resid[(size_t)m * N + n];
            }
            C[(size_t)m * N + n] = z;
        }
    }
}

// ---------------------------------------------------------------------------
// LayerNorm + adaLN modulation.
// ---------------------------------------------------------------------------
__global__ __launch_bounds__(256) void ln_mod_k(
    const float* __restrict__ x, const float* __restrict__ w,
    const float* __restrict__ b, const float* __restrict__ scp,
    const float* __restrict__ shp, int bstride, float eps,
    float* __restrict__ out)
{
    const int row = blockIdx.x;
    const int tid = threadIdx.x;
    const int bb = row >> 10;
    const float* xr = x + (size_t)row * E_;
    float4 v = ((const float4*)xr)[tid];
    float xv[4] = {v.x, v.y, v.z, v.w};
    float s = xv[0] + xv[1] + xv[2] + xv[3];
    float sq = xv[0] * xv[0] + xv[1] * xv[1] + xv[2] * xv[2] + xv[3] * xv[3];
    __shared__ float r1[256], r2[256];
    r1[tid] = s; r2[tid] = sq;
    __syncthreads();
    for (int o = 128; o > 0; o >>= 1) {
        if (tid < o) { r1[tid] += r1[tid + o]; r2[tid] += r2[tid + o]; }
        __syncthreads();
    }
    const float mean = r1[0] * (1.f / E_);
    const float var = r2[0] * (1.f / E_) - mean * mean;
    const float rs = rsqrtf(var + eps);
#pragma unroll
    for (int l = 0; l < 4; ++l) {
        const int e = tid * 4 + l;
        float y = (xv[l] - mean) * rs;
        if (w) y = y * w[e] + b[e];
        y = y * (1.f + scp[(size_t)bb * bstride + e]) + shp[(size_t)bb * bstride + e];
        out[(size_t)row * E_ + e] = y;
    }
}

// ---------------------------------------------------------------------------
// Rotary on q and k, in place.
// ---------------------------------------------------------------------------
__global__ __launch_bounds__(256) void rotary_k(float* __restrict__ qkv)
{
    const int idx = blockIdx.x * 256 + threadIdx.x;
    const int j = idx & 15;
    const int hh = (idx >> 4) & 15;
    const int si = (idx >> 8) & 1023;
    const int b = idx >> 18;
    const float ang = (float)si * powf(10000.f, -(float)j * (1.f / 16.f));
    float sn, cs;
    sincosf(ang, &sn, &cs);
    float* base = qkv + ((size_t)(b * S_ + si)) * (3 * E_) + hh * 64 + 2 * j;
    float x1 = base[0], x2 = base[1];
    base[0] = x1 * cs - x2 * sn;
    base[1] = x2 * cs + x1 * sn;
    float* kb = base + E_;
    x1 = kb[0]; x2 = kb[1];
    kb[0] = x1 * cs - x2 * sn;
    kb[1] = x2 * cs + x1 * sn;
}

// ---------------------------------------------------------------------------
// lambda per block.
// ---------------------------------------------------------------------------
__global__ __launch_bounds__(256) void lam_k(
    const float* __restrict__ lq1, const float* __restrict__ lk1,
    const float* __restrict__ lq2, const float* __restrict__ lk2,
    float* __restrict__ lamout, float li0, float li1, float li2, float li3)
{
    const int w = threadIdx.x >> 6, lane = threadIdx.x & 63;
    float s1 = lq1[w * 64 + lane] * lk1[w * 64 + lane];
    float s2 = lq2[w * 64 + lane] * lk2[w * 64 + lane];
    for (int o = 32; o > 0; o >>= 1) {
        s1 += __shfl_down(s1, o);
        s2 += __shfl_down(s2, o);
    }
    if (lane == 0) {
        float li = (w == 0) ? li0 : (w == 1) ? li1 : (w == 2) ? li2 : li3;
        lamout[w] = expf(s1) - expf(s2) + li;
    }
}

// ---------------------------------------------------------------------------
// Tiny GEMM for modulation.
// ---------------------------------------------------------------------------
__global__ __launch_bounds__(256) void small_gemm_k(
    const float* __restrict__ emb, const float* __restrict__ W,
    const float* __restrict__ bias, float* __restrict__ out, int N)
{
    const int idx = blockIdx.x * 256 + threadIdx.x;
    const int b = idx / N, n = idx % N;
    const float* er = emb + (size_t)b * E_;
    float acc = bias[n];
#pragma unroll 8
    for (int k = 0; k < E_; ++k) acc += er[k] * W[(size_t)k * N + n];
    out[idx] = acc;
}

// ---------------------------------------------------------------------------
// Flash differential attention with bf16 MFMA.
// Grid (16 q-tiles, H=8, B=2), 256 threads (4 waves); wave w owns query
// sub-tile of 16 rows. Per j-tile of 32 keys: stage K/V (bf16), scores via
// mfma_f32_16x16x32_bf16, online 2-component softmax, P through LDS (bf16,
// wave-private rows -> no barrier), PV via MFMA vs transposed V. Epilogue:
// A1-lam*A2, RMSNorm(aln_w,aln_b), *(1-lam_init).
// ---------------------------------------------------------------------------
__global__ __launch_bounds__(256) void fattn_k(
    const float* __restrict__ qkv, const float* __restrict__ lamptr,
    const float* __restrict__ alnw, const float* __restrict__ alnb,
    float* __restrict__ out, float omli)
{
    const int qt = blockIdx.x, h = blockIdx.y, b = blockIdx.z;
    const int tid = threadIdx.x;
    const int w = tid >> 6, lane = tid & 63, quad = lane >> 4, l16 = lane & 15;

    __shared__ __align__(16) short Qs[64 * 136];   // [row][dim0..127], stride 136
    __shared__ __align__(16) short Ks[32 * 136];
    __shared__ __align__(16) short Vt[128 * 40];   // [e][j], stride 40
    __shared__ __align__(16) short P1[64 * 40];    // [i][j], stride 40
    __shared__ __align__(16) short P2[64 * 40];

    const size_t base = ((size_t)b * S_) * (3 * E_);

    // ---- stage Q (rows qt*64..+63), fp32 -> bf16 ----
    {
        const int row = tid >> 2, dg = (tid & 3) * 32;
        const float* src = qkv + base + (size_t)(qt * 64 + row) * (3 * E_) + h * 128 + dg;
#pragma unroll
        for (int k = 0; k < 32; k += 4) {
            float4 v = *(const float4*)(src + k);
            sh4 p = {f2bf(v.x), f2bf(v.y), f2bf(v.z), f2bf(v.w)};
            *(sh4*)&Qs[row * 136 + dg + k] = p;
        }
    }
    __syncthreads();

    // ---- hoist Q A-fragments (wave-private rows) ----
    bf16x8 qf[4];
    {
        const int qrow = w * 16 + l16;
#pragma unroll
        for (int d = 0; d < 4; ++d)
            qf[d] = *(const bf16x8*)&Qs[qrow * 136 + d * 32 + quad * 8];
    }

    float m1[4], l1[4], m2[4], l2[4];
    f32x4 o1[8], o2[8];
#pragma unroll
    for (int r = 0; r < 4; ++r) { m1[r] = -3e38f; m2[r] = -3e38f; l1[r] = 0.f; l2[r] = 0.f; }
#pragma unroll
    for (int es = 0; es < 8; ++es) { o1[es] = (f32x4)0.f; o2[es] = (f32x4)0.f; }

    const int irow0 = qt * 64 + w * 16 + quad * 4;
    const int jt_end = 2 * qt + 2;

    for (int jt = 0; jt < jt_end; ++jt) {
        __syncthreads();  // protect Ks/Vt from previous iteration's readers
        // ---- stage K and V(transposed) for rows jt*32..+31 ----
        {
            const int row = tid >> 3, dg = (tid & 7) * 16;
            const float* ksrc = qkv + base + (size_t)(jt * 32 + row) * (3 * E_) + E_ + h * 128 + dg;
            const float* vsrc = ksrc + E_;
#pragma unroll
            for (int k = 0; k < 16; k += 4) {
                float4 v = *(const float4*)(ksrc + k);
                sh4 p = {f2bf(v.x), f2bf(v.y), f2bf(v.z), f2bf(v.w)};
                *(sh4*)&Ks[row * 136 + dg + k] = p;
            }
#pragma unroll
            for (int k = 0; k < 16; k += 4) {
                float4 v = *(const float4*)(vsrc + k);
                Vt[(dg + k + 0) * 40 + row] = f2bf(v.x);
                Vt[(dg + k + 1) * 40 + row] = f2bf(v.y);
                Vt[(dg + k + 2) * 40 + row] = f2bf(v.z);
                Vt[(dg + k + 3) * 40 + row] = f2bf(v.w);
            }
        }
        __syncthreads();

        // ---- scores: S[i][j] for 2 jsub x 2 components ----
        f32x4 s1[2], s2[2];
#pragma unroll
        for (int jsub = 0; jsub < 2; ++jsub) {
            const short* kb = &Ks[(jsub * 16 + l16) * 136 + quad * 8];
            bf16x8 b0 = *(const bf16x8*)(kb + 0);
            bf16x8 b1 = *(const bf16x8*)(kb + 32);
            bf16x8 b2 = *(const bf16x8*)(kb + 64);
            bf16x8 b3 = *(const bf16x8*)(kb + 96);
            f32x4 a = (f32x4)0.f;
            a = __builtin_amdgcn_mfma_f32_16x16x32_bf16(qf[0], b0, a, 0, 0, 0);
            a = __builtin_amdgcn_mfma_f32_16x16x32_bf16(qf[1], b1, a, 0, 0, 0);
            s1[jsub] = a;
            f32x4 c = (f32x4)0.f;
            c = __builtin_amdgcn_mfma_f32_16x16x32_bf16(qf[2], b2, c, 0, 0, 0);
            c = __builtin_amdgcn_mfma_f32_16x16x32_bf16(qf[3], b3, c, 0, 0, 0);
            s2[jsub] = c;
        }
        // scale + causal mask (only needed on the last two tiles)
        const bool diag = (jt >= 2 * qt);
#pragma unroll
        for (int jsub = 0; jsub < 2; ++jsub) {
            const int jbase = jt * 32 + jsub * 16 + l16;
#pragma unroll
            for (int r = 0; r < 4; ++r) {
                float v1 = s1[jsub][r] * 0.125f;
                float v2 = s2[jsub][r] * 0.125f;
                if (diag && jbase > irow0 + r) { v1 = -3e38f; v2 = -3e38f; }
                s1[jsub][r] = v1; s2[jsub][r] = v2;
            }
        }

        // ---- online softmax update, both components ----
#pragma unroll
        for (int comp = 0; comp < 2; ++comp) {
            f32x4* s = comp ? s2 : s1;
            float* m = comp ? m2 : m1;
            float* l = comp ? l2 : l1;
            f32x4* o = comp ? o2 : o1;
            short* P = comp ? P2 : P1;

            f32x4 rm;
#pragma unroll
            for (int r = 0; r < 4; ++r) rm[r] = fmaxf(s[0][r], s[1][r]);
#pragma unroll
            for (int off = 1; off < 16; off <<= 1) {
#pragma unroll
                for (int r = 0; r < 4; ++r) rm[r] = fmaxf(rm[r], __shfl_xor(rm[r], off));
            }
            float al[4];
#pragma unroll
            for (int r = 0; r < 4; ++r) {
                float mn = fmaxf(m[r], rm[r]);
                al[r] = expf(m[r] - mn);
                m[r] = mn;
            }
            f32x4 p0, p1;
#pragma unroll
            for (int r = 0; r < 4; ++r) {
                p0[r] = expf(s[0][r] - m[r]);
                p1[r] = expf(s[1][r] - m[r]);
            }
            f32x4 rs;
#pragma unroll
            for (int r = 0; r < 4; ++r) rs[r] = p0[r] + p1[r];
#pragma unroll
            for (int off = 1; off < 16; off <<= 1) {
#pragma unroll
                for (int r = 0; r < 4; ++r) rs[r] += __shfl_xor(rs[r], off);
            }
#pragma unroll
            for (int r = 0; r < 4; ++r) l[r] = l[r] * al[r] + rs[r];
#pragma unroll
            for (int es = 0; es < 8; ++es)
#pragma unroll
                for (int r = 0; r < 4; ++r) o[es][r] *= al[r];
            // write P (wave-private rows; no barrier needed before PV)
            const int prow = (w * 16 + quad * 4) * 40 + l16;
#pragma unroll
            for (int r = 0; r < 4; ++r) {
                P[prow + r * 40]      = f2bf(p0[r]);
                P[prow + r * 40 + 16] = f2bf(p1[r]);
            }
        }

        // ---- PV: O += P * V ----
        bf16x8 a1 = *(const bf16x8*)&P1[(w * 16 + l16) * 40 + quad * 8];
        bf16x8 a2 = *(const bf16x8*)&P2[(w * 16 + l16) * 40 + quad * 8];
#pragma unroll
        for (int es = 0; es < 8; ++es) {
            bf16x8 vb = *(const bf16x8*)&Vt[(es * 16 + l16) * 40 + quad * 8];
            o1[es] = __builtin_amdgcn_mfma_f32_16x16x32_bf16(a1, vb, o1[es], 0, 0, 0);
            o2[es] = __builtin_amdgcn_mfma_f32_16x16x32_bf16(a2, vb, o2[es], 0, 0, 0);
        }
    }

    // ---- epilogue: D = A1 - lam*A2, RMSNorm, scale, store ----
    const float lam = *lamptr;
    float il1[4], il2[4];
#pragma unroll
    for (int r = 0; r < 4; ++r) { il1[r] = 1.f / l1[r]; il2[r] = lam / l2[r]; }
    f32x4 dsq = (f32x4)0.f;
#pragma unroll
    for (int es = 0; es < 8; ++es) {
#pragma unroll
        for (int r = 0; r < 4; ++r) {
            float d = o1[es][r] * il1[r] - o2[es][r] * il2[r];
            o1[es][r] = d;
            dsq[r] += d * d;
        }
    }
#pragma unroll
    for (int off = 1; off < 16; off <<= 1) {
#pragma unroll
        for (int r = 0; r < 4; ++r) dsq[r] += __shfl_xor(dsq[r], off);
    }
    float rsv[4];
#pragma unroll
    for (int r = 0; r < 4; ++r) rsv[r] = rsqrtf(dsq[r] * (1.f / 128.f) + 1e-8f);

#pragma unroll
    for (int es = 0; es < 8; ++es) {
        const int e = es * 16 + l16;
        const float wv = alnw[e], bv = alnb[e];
#pragma unroll
        for (int r = 0; r < 4; ++r) {
            const int i = irow0 + r;
            float ov = (o1[es][r] * rsv[r] * wv + bv) * omli;
            out[((size_t)b * S_ + i) * E_ + h * 128 + e] = ov;
        }
    }
}

// ---------------------------------------------------------------------------
extern "C" void kernel_launch(void* const* d_in, const int* in_sizes, int n_in,
                              void* d_out, int out_size, void* d_ws, size_t ws_size,
                              hipStream_t stream)
{
    const float* x      = (const float*)d_in[0];
    const float* emb    = (const float*)d_in[1];
    const float* l2e_w1 = (const float*)d_in[2];
    const float* l2e_b1 = (const float*)d_in[3];
    const float* l2e_al = (const float*)d_in[4];
    const float* l2e_be = (const float*)d_in[5];
    const float* l2e_w2 = (const float*)d_in[6];
    const float* l2e_b2 = (const float*)d_in[7];
    const float* ln1_w  = (const float*)d_in[8];
    const float* ln1_b  = (const float*)d_in[9];
    const float* ln2_w  = (const float*)d_in[10];
    const float* ln2_b  = (const float*)d_in[11];
    const float* qkv_w  = (const float*)d_in[12];
    const float* out_w  = (const float*)d_in[13];
    const float* lq1    = (const float*)d_in[14];
    const float* lk1    = (const float*)d_in[15];
    const float* lq2    = (const float*)d_in[16];
    const float* lk2    = (const float*)d_in[17];
    const float* aln_w  = (const float*)d_in[18];
    const float* aln_b  = (const float*)d_in[19];
    const float* ada_w  = (const float*)d_in[20];
    const float* ada_b  = (const float*)d_in[21];
    const float* ff_w1  = (const float*)d_in[22];
    const float* ff_b1  = (const float*)d_in[23];
    const float* ff_al  = (const float*)d_in[24];
    const float* ff_be  = (const float*)d_in[25];
    const float* ff_w2  = (const float*)d_in[26];
    const float* ff_b2  = (const float*)d_in[27];
    const float* adaf_w = (const float*)d_in[28];
    const float* adaf_b = (const float*)d_in[29];
    const float* fin_w  = (const float*)d_in[30];
    const float* fin_b  = (const float*)d_in[31];
    float* outp = (float*)d_out;

    const int M = B_ * S_;               // 2048
    const size_t MN = (size_t)M * E_;
    float* ws    = (float*)d_ws;
    float* hbuf  = ws;                   // MN
    float* tbuf  = ws + MN;              // MN
    float* big   = ws + 2 * MN;          // 4*MN
    float* abuf  = ws + 6 * MN;          // MN
    float* mods  = abuf + MN;            // 4 * B_ * 6E
    float* adafm = mods + 4 * B_ * 6 * E_;
    float* lamb  = adafm + B_ * 2 * E_;

    double li[4];
    for (int i = 0; i < 4; ++i) li[i] = 0.8 - 0.6 * exp(-0.3 * (i + 1));

    lam_k<<<1, 256, 0, stream>>>(lq1, lk1, lq2, lk2, lamb,
                                 (float)li[0], (float)li[1], (float)li[2], (float)li[3]);
    for (int i = 0; i < 4; ++i)
        small_gemm_k<<<(B_ * 6 * E_) / 256, 256, 0, stream>>>(
            emb, ada_w + (size_t)i * E_ * 6 * E_, ada_b + (size_t)i * 6 * E_,
            mods + (size_t)i * B_ * 6 * E_, 6 * E_);
    small_gemm_k<<<(B_ * 2 * E_) / 256, 256, 0, stream>>>(emb, adaf_w, adaf_b, adafm, 2 * E_);

    gemm_k<1><<<dim3(E_ / 64, M / 64), 256, 0, stream>>>(
        x, l2e_w1, l2e_b1, tbuf, M, E_, 64, l2e_al, l2e_be, nullptr, 0);
    gemm_k<0><<<dim3(E_ / 64, M / 64), 256, 0, stream>>>(
        tbuf, l2e_w2, l2e_b2, hbuf, M, E_, E_, nullptr, nullptr, nullptr, 0);

    for (int i = 0; i < 4; ++i) {
        const float* mi = mods + (size_t)i * B_ * 6 * E_;
        const float omli = 1.f - (float)li[i];

        ln_mod_k<<<M, 256, 0, stream>>>(hbuf, ln1_w + i * E_, ln1_b + i * E_,
                                        mi, mi + E_, 6 * E_, 1e-5f, tbuf);
        gemm_k<0><<<dim3(3 * E_ / 64, M / 64), 256, 0, stream>>>(
            tbuf, qkv_w + (size_t)i * E_ * 3 * E_, nullptr, big, M, 3 * E_, E_,
            nullptr, nullptr, nullptr, 0);
        rotary_k<<<(B_ * S_ * 16 * 16) / 256, 256, 0, stream>>>(big);
        fattn_k<<<dim3(16, 8, B_), 256, 0, stream>>>(
            big, lamb + i, aln_w + i * 128, aln_b + i * 128, abuf, omli);
        gemm_k<2><<<dim3(E_ / 64, M / 64), 256, 0, stream>>>(
            abuf, out_w + (size_t)i * E_ * E_, nullptr, hbuf, M, E_, E_,
            mi + 4 * E_, nullptr, hbuf, 6 * E_);

        ln_mod_k<<<M, 256, 0, stream>>>(hbuf, ln2_w + i * E_, ln2_b + i * E_,
                                        mi + 2 * E_, mi + 3 * E_, 6 * E_, 1e-5f, tbuf);
        gemm_k<1><<<dim3(4 * E_ / 64, M / 64), 256, 0, stream>>>(
            tbuf, ff_w1 + (size_t)i * E_ * 4 * E_, ff_b1 + i * 4 * E_, big,
            M, 4 * E_, E_, ff_al + i * 4 * E_, ff_be + i * 4 * E_, nullptr, 0);
        gemm_k<2><<<dim3(E_ / 64, M / 64), 256, 0, stream>>>(
            big, ff_w2 + (size_t)i * 4 * E_ * E_, ff_b2 + i * E_, hbuf,
            M, E_, 4 * E_, mi + 5 * E_, nullptr, hbuf, 6 * E_);
    }

    ln_mod_k<<<M, 256, 0, stream>>>(hbuf, nullptr, nullptr, adafm, adafm + E_,
                                    2 * E_, 1e-6f, tbuf);
    gemm_k<0><<<dim3(1, M / 64), 256, 0, stream>>>(
        tbuf, fin_w, fin_b, outp, M, 64, E_, nullptr, nullptr, nullptr, 0);
}

// Round 3
// 3081.131 us; speedup vs baseline: 3.7438x; 1.8645x over previous
//
#include <hip/hip_runtime.h>
#include <math.h>

// Problem constants (B,S,LAT,E,H,NB) = (2,1024,64,1024,8,4); HD=64, ROT=32.
#define B_ 2
#define S_ 1024
#define E_ 1024

typedef __attribute__((ext_vector_type(8))) short bf16x8;
typedef __attribute__((ext_vector_type(4))) float f32x4;
typedef __attribute__((ext_vector_type(4))) short sh4;

typedef __attribute__((address_space(1))) const unsigned int gu32;
typedef __attribute__((address_space(3))) unsigned int lu32;

__device__ __forceinline__ short f2bf(float x) {
    unsigned u = __float_as_uint(x);
    unsigned r = (u + 0x7FFFu + ((u >> 16) & 1u)) >> 16;
    return (short)r;
}

__device__ __forceinline__ void gld_lds16(const void* g, void* l) {
    __builtin_amdgcn_global_load_lds((gu32*)g, (lu32*)l, 16, 0, 0);
}

// ---------------------------------------------------------------------------
// Weight transpose-convert: W fp32 [K,N] -> Wt bf16 [N,K].
// grid (N/64, K/64), 256 threads.
// ---------------------------------------------------------------------------
__global__ __launch_bounds__(256) void wcvt_k(
    const float* __restrict__ W, short* __restrict__ Wt, int K, int N)
{
    __shared__ short L[64][80];
    const int n0 = blockIdx.x * 64, k0 = blockIdx.y * 64;
    const int t = threadIdx.x;
    const int kr = t >> 4, nc = (t & 15) * 4;
#pragma unroll
    for (int r = 0; r < 4; ++r) {
        const int k = kr + r * 16;
        float4 v = *(const float4*)(W + (size_t)(k0 + k) * N + n0 + nc);
        L[nc + 0][k] = f2bf(v.x); L[nc + 1][k] = f2bf(v.y);
        L[nc + 2][k] = f2bf(v.z); L[nc + 3][k] = f2bf(v.w);
    }
    __syncthreads();
    const int nr = t >> 2, kc = (t & 3) * 16;
    short* dst = Wt + (size_t)(n0 + nr) * K + k0 + kc;
    *(bf16x8*)dst = *(bf16x8*)&L[nr][kc];
    *(bf16x8*)(dst + 8) = *(bf16x8*)&L[nr][kc + 8];
}

// ---------------------------------------------------------------------------
// bf16 MFMA GEMM: C[M,N] = A[M,K] @ Wt[N,K]^T  (+bias, epilogue MODE).
// m97 structure: global_load_lds(16B) staging, 16x16x32 bf16 MFMA.
// Block tile TM x TN, 4 waves in WGM x WGN grid, BK=32.
// MODE 0: plain. MODE 1: snake (per-col alpha/beta). MODE 2: z*sigmoid(1-gate)+resid.
// OBF: store bf16 (short) instead of fp32.
// ---------------------------------------------------------------------------
template <int TM, int TN, int WGM, int WGN, int MODE, bool OBF>
__global__ __launch_bounds__(256) void mgemm_k(
    const short* __restrict__ A, const short* __restrict__ Wt,
    const float* __restrict__ bias, void* __restrict__ Cout,
    int M, int N, int K,
    const float* __restrict__ e1, const float* __restrict__ e2,
    const float* __restrict__ resid, int estride)
{
    constexpr int WM = TM / WGM;
    constexpr int WN = TN / WGN;
    constexpr int MI = WM / 16;
    constexpr int NI = WN / 16;
    __shared__ __align__(16) short As[TM * 32];
    __shared__ __align__(16) short Bs[TN * 32];
    const int tid = threadIdx.x;
    const int w = tid >> 6, lane = tid & 63, quad = lane >> 4, l16 = lane & 15;
    const int wr = w / WGN, wc = w % WGN;
    const int bm = blockIdx.y * TM, bn = blockIdx.x * TN;
    const int arow = tid >> 2, ak = (tid & 3) * 8;

    f32x4 acc[MI][NI] = {};

    for (int k0 = 0; k0 < K; k0 += 32) {
        __syncthreads();
#pragma unroll
        for (int i = 0; i < TM / 64; ++i)
            gld_lds16(A + (size_t)(bm + i * 64 + arow) * K + k0 + ak,
                      As + i * 2048 + tid * 8);
#pragma unroll
        for (int i = 0; i < TN / 64; ++i)
            gld_lds16(Wt + (size_t)(bn + i * 64 + arow) * K + k0 + ak,
                      Bs + i * 2048 + tid * 8);
        __syncthreads();

        bf16x8 af[MI], bfr[NI];
#pragma unroll
        for (int mi = 0; mi < MI; ++mi)
            af[mi] = *(const bf16x8*)&As[(wr * WM + mi * 16 + l16) * 32 + quad * 8];
#pragma unroll
        for (int ni = 0; ni < NI; ++ni)
            bfr[ni] = *(const bf16x8*)&Bs[(wc * WN + ni * 16 + l16) * 32 + quad * 8];
#pragma unroll
        for (int mi = 0; mi < MI; ++mi)
#pragma unroll
            for (int ni = 0; ni < NI; ++ni)
                acc[mi][ni] = __builtin_amdgcn_mfma_f32_16x16x32_bf16(
                    af[mi], bfr[ni], acc[mi][ni], 0, 0, 0);
    }

#pragma unroll
    for (int mi = 0; mi < MI; ++mi) {
#pragma unroll
        for (int ni = 0; ni < NI; ++ni) {
            const int col = bn + wc * WN + ni * 16 + l16;
            const float bv = bias ? bias[col] : 0.f;
#pragma unroll
            for (int r = 0; r < 4; ++r) {
                const int row = bm + wr * WM + mi * 16 + quad * 4 + r;
                float z = acc[mi][ni][r] + bv;
                if (MODE == 1) {
                    float s = sinf(e1[col] * z);
                    z = z + s * s / (e2[col] + 1e-9f);
                } else if (MODE == 2) {
                    const int bb = row >> 10;
                    const float g = e1[(size_t)bb * estride + col];
                    z = z / (1.f + expf(g - 1.f)) + resid[(size_t)row * N + col];
                }
                if (OBF) ((short*)Cout)[(size_t)row * N + col] = f2bf(z);
                else     ((float*)Cout)[(size_t)row * N + col] = z;
            }
        }
    }
}

// ---------------------------------------------------------------------------
// fp32 tiled GEMM (small shapes: l2e gemm1 K=64, fin N=64).
// ---------------------------------------------------------------------------
constexpr int BM = 64, BN = 64, BK = 16;

template <int MODE, bool OBF>
__global__ __launch_bounds__(256) void gemm_k(
    const float* __restrict__ A, const float* __restrict__ W,
    const float* __restrict__ bias, void* __restrict__ Cout,
    int M, int N, int K,
    const float* __restrict__ e1, const float* __restrict__ e2)
{
    __shared__ float As[BK][BM + 1];
    __shared__ float Ws[BK][BN + 1];
    const int tid = threadIdx.x;
    const int bn = blockIdx.x * BN;
    const int bm = blockIdx.y * BM;
    const int tx = tid & 15, ty = tid >> 4;

    const int am = tid >> 2;
    const int ak = (tid & 3) * 4;
    const int wk = tid >> 4;
    const int wn = (tid & 15) * 4;

    float acc[4][4] = {};

    for (int k0 = 0; k0 < K; k0 += BK) {
        float4 a4 = *(const float4*)(A + (size_t)(bm + am) * K + k0 + ak);
        float4 w4 = *(const float4*)(W + (size_t)(k0 + wk) * N + bn + wn);
        As[ak + 0][am] = a4.x; As[ak + 1][am] = a4.y;
        As[ak + 2][am] = a4.z; As[ak + 3][am] = a4.w;
        Ws[wk][wn + 0] = w4.x; Ws[wk][wn + 1] = w4.y;
        Ws[wk][wn + 2] = w4.z; Ws[wk][wn + 3] = w4.w;
        __syncthreads();
#pragma unroll
        for (int kk = 0; kk < BK; ++kk) {
            float a[4], b[4];
#pragma unroll
            for (int r = 0; r < 4; ++r) a[r] = As[kk][ty * 4 + r];
#pragma unroll
            for (int c = 0; c < 4; ++c) b[c] = Ws[kk][tx * 4 + c];
#pragma unroll
            for (int r = 0; r < 4; ++r)
#pragma unroll
                for (int c = 0; c < 4; ++c) acc[r][c] += a[r] * b[c];
        }
        __syncthreads();
    }

#pragma unroll
    for (int r = 0; r < 4; ++r) {
        const int m = bm + ty * 4 + r;
#pragma unroll
        for (int c = 0; c < 4; ++c) {
            const int n = bn + tx * 4 + c;
            float z = acc[r][c];
            if (bias) z += bias[n];
            if (MODE == 1) {
                float s = sinf(e1[n] * z);
                z = z + s * s / (e2[n] + 1e-9f);
            }
            if (OBF) ((short*)Cout)[(size_t)m * N + n] = f2bf(z);
            else     ((float*)Cout)[(size_t)m * N + n] = z;
        }
    }
}

// ---------------------------------------------------------------------------
// LayerNorm + adaLN modulation; output fp32 or bf16.
// ---------------------------------------------------------------------------
template <bool OBF>
__global__ __launch_bounds__(256) void ln_mod_k(
    const float* __restrict__ x, const float* __restrict__ w,
    const float* __restrict__ b, const float* __restrict__ scp,
    const float* __restrict__ shp, int bstride, float eps,
    void* __restrict__ out)
{
    const int row = blockIdx.x;
    const int tid = threadIdx.x;
    const int bb = row >> 10;
    const float* xr = x + (size_t)row * E_;
    float4 v = ((const float4*)xr)[tid];
    float xv[4] = {v.x, v.y, v.z, v.w};
    float s = xv[0] + xv[1] + xv[2] + xv[3];
    float sq = xv[0] * xv[0] + xv[1] * xv[1] + xv[2] * xv[2] + xv[3] * xv[3];
    __shared__ float r1[256], r2[256];
    r1[tid] = s; r2[tid] = sq;
    __syncthreads();
    for (int o = 128; o > 0; o >>= 1) {
        if (tid < o) { r1[tid] += r1[tid + o]; r2[tid] += r2[tid + o]; }
        __syncthreads();
    }
    const float mean = r1[0] * (1.f / E_);
    const float var = r2[0] * (1.f / E_) - mean * mean;
    const float rs = rsqrtf(var + eps);
    float yv[4];
#pragma unroll
    for (int l = 0; l < 4; ++l) {
        const int e = tid * 4 + l;
        float y = (xv[l] - mean) * rs;
        if (w) y = y * w[e] + b[e];
        yv[l] = y * (1.f + scp[(size_t)bb * bstride + e]) + shp[(size_t)bb * bstride + e];
    }
    if (OBF) {
        sh4 p = {f2bf(yv[0]), f2bf(yv[1]), f2bf(yv[2]), f2bf(yv[3])};
        *(sh4*)((short*)out + (size_t)row * E_ + tid * 4) = p;
    } else {
        float4 p = {yv[0], yv[1], yv[2], yv[3]};
        *(float4*)((float*)out + (size_t)row * E_ + tid * 4) = p;
    }
}

// ---------------------------------------------------------------------------
// Rotary on q and k, in place (fp32 qkv buffer).
// ---------------------------------------------------------------------------
__global__ __launch_bounds__(256) void rotary_k(float* __restrict__ qkv)
{
    const int idx = blockIdx.x * 256 + threadIdx.x;
    const int j = idx & 15;
    const int hh = (idx >> 4) & 15;
    const int si = (idx >> 8) & 1023;
    const int b = idx >> 18;
    const float ang = (float)si * powf(10000.f, -(float)j * (1.f / 16.f));
    float sn, cs;
    sincosf(ang, &sn, &cs);
    float* base = qkv + ((size_t)(b * S_ + si)) * (3 * E_) + hh * 64 + 2 * j;
    float x1 = base[0], x2 = base[1];
    base[0] = x1 * cs - x2 * sn;
    base[1] = x2 * cs + x1 * sn;
    float* kb = base + E_;
    x1 = kb[0]; x2 = kb[1];
    kb[0] = x1 * cs - x2 * sn;
    kb[1] = x2 * cs + x1 * sn;
}

// ---------------------------------------------------------------------------
// lambda per block.
// ---------------------------------------------------------------------------
__global__ __launch_bounds__(256) void lam_k(
    const float* __restrict__ lq1, const float* __restrict__ lk1,
    const float* __restrict__ lq2, const float* __restrict__ lk2,
    float* __restrict__ lamout, float li0, float li1, float li2, float li3)
{
    const int w = threadIdx.x >> 6, lane = threadIdx.x & 63;
    float s1 = lq1[w * 64 + lane] * lk1[w * 64 + lane];
    float s2 = lq2[w * 64 + lane] * lk2[w * 64 + lane];
    for (int o = 32; o > 0; o >>= 1) {
        s1 += __shfl_down(s1, o);
        s2 += __shfl_down(s2, o);
    }
    if (lane == 0) {
        float li = (w == 0) ? li0 : (w == 1) ? li1 : (w == 2) ? li2 : li3;
        lamout[w] = expf(s1) - expf(s2) + li;
    }
}

// ---------------------------------------------------------------------------
// Tiny GEMM for modulation.
// ---------------------------------------------------------------------------
__global__ __launch_bounds__(256) void small_gemm_k(
    const float* __restrict__ emb, const float* __restrict__ W,
    const float* __restrict__ bias, float* __restrict__ out, int N)
{
    const int idx = blockIdx.x * 256 + threadIdx.x;
    const int b = idx / N, n = idx % N;
    const float* er = emb + (size_t)b * E_;
    float acc = bias[n];
#pragma unroll 8
    for (int k = 0; k < E_; ++k) acc += er[k] * W[(size_t)k * N + n];
    out[idx] = acc;
}

// ---------------------------------------------------------------------------
// Flash differential attention with bf16 MFMA (output bf16).
// ---------------------------------------------------------------------------
__global__ __launch_bounds__(256) void fattn_k(
    const float* __restrict__ qkv, const float* __restrict__ lamptr,
    const float* __restrict__ alnw, const float* __restrict__ alnb,
    short* __restrict__ out, float omli)
{
    const int qt = blockIdx.x, h = blockIdx.y, b = blockIdx.z;
    const int tid = threadIdx.x;
    const int w = tid >> 6, lane = tid & 63, quad = lane >> 4, l16 = lane & 15;

    __shared__ __align__(16) short Qs[64 * 136];
    __shared__ __align__(16) short Ks[32 * 136];
    __shared__ __align__(16) short Vt[128 * 40];
    __shared__ __align__(16) short P1[64 * 40];
    __shared__ __align__(16) short P2[64 * 40];

    const size_t base = ((size_t)b * S_) * (3 * E_);

    {
        const int row = tid >> 2, dg = (tid & 3) * 32;
        const float* src = qkv + base + (size_t)(qt * 64 + row) * (3 * E_) + h * 128 + dg;
#pragma unroll
        for (int k = 0; k < 32; k += 4) {
            float4 v = *(const float4*)(src + k);
            sh4 p = {f2bf(v.x), f2bf(v.y), f2bf(v.z), f2bf(v.w)};
            *(sh4*)&Qs[row * 136 + dg + k] = p;
        }
    }
    __syncthreads();

    bf16x8 qf[4];
    {
        const int qrow = w * 16 + l16;
#pragma unroll
        for (int d = 0; d < 4; ++d)
            qf[d] = *(const bf16x8*)&Qs[qrow * 136 + d * 32 + quad * 8];
    }

    float m1[4], l1[4], m2[4], l2[4];
    f32x4 o1[8], o2[8];
#pragma unroll
    for (int r = 0; r < 4; ++r) { m1[r] = -3e38f; m2[r] = -3e38f; l1[r] = 0.f; l2[r] = 0.f; }
#pragma unroll
    for (int es = 0; es < 8; ++es) { o1[es] = (f32x4)0.f; o2[es] = (f32x4)0.f; }

    const int irow0 = qt * 64 + w * 16 + quad * 4;
    const int jt_end = 2 * qt + 2;

    for (int jt = 0; jt < jt_end; ++jt) {
        __syncthreads();
        {
            const int row = tid >> 3, dg = (tid & 7) * 16;
            const float* ksrc = qkv + base + (size_t)(jt * 32 + row) * (3 * E_) + E_ + h * 128 + dg;
            const float* vsrc = ksrc + E_;
#pragma unroll
            for (int k = 0; k < 16; k += 4) {
                float4 v = *(const float4*)(ksrc + k);
                sh4 p = {f2bf(v.x), f2bf(v.y), f2bf(v.z), f2bf(v.w)};
                *(sh4*)&Ks[row * 136 + dg + k] = p;
            }
#pragma unroll
            for (int k = 0; k < 16; k += 4) {
                float4 v = *(const float4*)(vsrc + k);
                Vt[(dg + k + 0) * 40 + row] = f2bf(v.x);
                Vt[(dg + k + 1) * 40 + row] = f2bf(v.y);
                Vt[(dg + k + 2) * 40 + row] = f2bf(v.z);
                Vt[(dg + k + 3) * 40 + row] = f2bf(v.w);
            }
        }
        __syncthreads();

        f32x4 s1[2], s2[2];
#pragma unroll
        for (int jsub = 0; jsub < 2; ++jsub) {
            const short* kb = &Ks[(jsub * 16 + l16) * 136 + quad * 8];
            bf16x8 b0 = *(const bf16x8*)(kb + 0);
            bf16x8 b1 = *(const bf16x8*)(kb + 32);
            bf16x8 b2 = *(const bf16x8*)(kb + 64);
            bf16x8 b3 = *(const bf16x8*)(kb + 96);
            f32x4 a = (f32x4)0.f;
            a = __builtin_amdgcn_mfma_f32_16x16x32_bf16(qf[0], b0, a, 0, 0, 0);
            a = __builtin_amdgcn_mfma_f32_16x16x32_bf16(qf[1], b1, a, 0, 0, 0);
            s1[jsub] = a;
            f32x4 c = (f32x4)0.f;
            c = __builtin_amdgcn_mfma_f32_16x16x32_bf16(qf[2], b2, c, 0, 0, 0);
            c = __builtin_amdgcn_mfma_f32_16x16x32_bf16(qf[3], b3, c, 0, 0, 0);
            s2[jsub] = c;
        }
        const bool diag = (jt >= 2 * qt);
#pragma unroll
        for (int jsub = 0; jsub < 2; ++jsub) {
            const int jbase = jt * 32 + jsub * 16 + l16;
#pragma unroll
            for (int r = 0; r < 4; ++r) {
                float v1 = s1[jsub][r] * 0.125f;
                float v2 = s2[jsub][r] * 0.125f;
                if (diag && jbase > irow0 + r) { v1 = -3e38f; v2 = -3e38f; }
                s1[jsub][r] = v1; s2[jsub][r] = v2;
            }
        }

#pragma unroll
        for (int comp = 0; comp < 2; ++comp) {
            f32x4* s = comp ? s2 : s1;
            float* m = comp ? m2 : m1;
            float* l = comp ? l2 : l1;
            f32x4* o = comp ? o2 : o1;
            short* P = comp ? P2 : P1;

            f32x4 rm;
#pragma unroll
            for (int r = 0; r < 4; ++r) rm[r] = fmaxf(s[0][r], s[1][r]);
#pragma unroll
            for (int off = 1; off < 16; off <<= 1) {
#pragma unroll
                for (int r = 0; r < 4; ++r) rm[r] = fmaxf(rm[r], __shfl_xor(rm[r], off));
            }
            float al[4];
#pragma unroll
            for (int r = 0; r < 4; ++r) {
                float mn = fmaxf(m[r], rm[r]);
                al[r] = expf(m[r] - mn);
                m[r] = mn;
            }
            f32x4 p0, p1;
#pragma unroll
            for (int r = 0; r < 4; ++r) {
                p0[r] = expf(s[0][r] - m[r]);
                p1[r] = expf(s[1][r] - m[r]);
            }
            f32x4 rs;
#pragma unroll
            for (int r = 0; r < 4; ++r) rs[r] = p0[r] + p1[r];
#pragma unroll
            for (int off = 1; off < 16; off <<= 1) {
#pragma unroll
                for (int r = 0; r < 4; ++r) rs[r] += __shfl_xor(rs[r], off);
            }
#pragma unroll
            for (int r = 0; r < 4; ++r) l[r] = l[r] * al[r] + rs[r];
#pragma unroll
            for (int es = 0; es < 8; ++es)
#pragma unroll
                for (int r = 0; r < 4; ++r) o[es][r] *= al[r];
            const int prow = (w * 16 + quad * 4) * 40 + l16;
#pragma unroll
            for (int r = 0; r < 4; ++r) {
                P[prow + r * 40]      = f2bf(p0[r]);
                P[prow + r * 40 + 16] = f2bf(p1[r]);
            }
        }

        bf16x8 a1 = *(const bf16x8*)&P1[(w * 16 + l16) * 40 + quad * 8];
        bf16x8 a2 = *(const bf16x8*)&P2[(w * 16 + l16) * 40 + quad * 8];
#pragma unroll
        for (int es = 0; es < 8; ++es) {
            bf16x8 vb = *(const bf16x8*)&Vt[(es * 16 + l16) * 40 + quad * 8];
            o1[es] = __builtin_amdgcn_mfma_f32_16x16x32_bf16(a1, vb, o1[es], 0, 0, 0);
            o2[es] = __builtin_amdgcn_mfma_f32_16x16x32_bf16(a2, vb, o2[es], 0, 0, 0);
        }
    }

    const float lam = *lamptr;
    float il1[4], il2[4];
#pragma unroll
    for (int r = 0; r < 4; ++r) { il1[r] = 1.f / l1[r]; il2[r] = lam / l2[r]; }
    f32x4 dsq = (f32x4)0.f;
#pragma unroll
    for (int es = 0; es < 8; ++es) {
#pragma unroll
        for (int r = 0; r < 4; ++r) {
            float d = o1[es][r] * il1[r] - o2[es][r] * il2[r];
            o1[es][r] = d;
            dsq[r] += d * d;
        }
    }
#pragma unroll
    for (int off = 1; off < 16; off <<= 1) {
#pragma unroll
        for (int r = 0; r < 4; ++r) dsq[r] += __shfl_xor(dsq[r], off);
    }
    float rsv[4];
#pragma unroll
    for (int r = 0; r < 4; ++r) rsv[r] = rsqrtf(dsq[r] * (1.f / 128.f) + 1e-8f);

#pragma unroll
    for (int es = 0; es < 8; ++es) {
        const int e = es * 16 + l16;
        const float wv = alnw[e], bv = alnb[e];
#pragma unroll
        for (int r = 0; r < 4; ++r) {
            const int i = irow0 + r;
            float ov = (o1[es][r] * rsv[r] * wv + bv) * omli;
            out[((size_t)b * S_ + i) * E_ + h * 128 + e] = f2bf(ov);
        }
    }
}

// ---------------------------------------------------------------------------
extern "C" void kernel_launch(void* const* d_in, const int* in_sizes, int n_in,
                              void* d_out, int out_size, void* d_ws, size_t ws_size,
                              hipStream_t stream)
{
    const float* x      = (const float*)d_in[0];
    const float* emb    = (const float*)d_in[1];
    const float* l2e_w1 = (const float*)d_in[2];
    const float* l2e_b1 = (const float*)d_in[3];
    const float* l2e_al = (const float*)d_in[4];
    const float* l2e_be = (const float*)d_in[5];
    const float* l2e_w2 = (const float*)d_in[6];
    const float* l2e_b2 = (const float*)d_in[7];
    const float* ln1_w  = (const float*)d_in[8];
    const float* ln1_b  = (const float*)d_in[9];
    const float* ln2_w  = (const float*)d_in[10];
    const float* ln2_b  = (const float*)d_in[11];
    const float* qkv_w  = (const float*)d_in[12];
    const float* out_w  = (const float*)d_in[13];
    const float* lq1    = (const float*)d_in[14];
    const float* lk1    = (const float*)d_in[15];
    const float* lq2    = (const float*)d_in[16];
    const float* lk2    = (const float*)d_in[17];
    const float* aln_w  = (const float*)d_in[18];
    const float* aln_b  = (const float*)d_in[19];
    const float* ada_w  = (const float*)d_in[20];
    const float* ada_b  = (const float*)d_in[21];
    const float* ff_w1  = (const float*)d_in[22];
    const float* ff_b1  = (const float*)d_in[23];
    const float* ff_al  = (const float*)d_in[24];
    const float* ff_be  = (const float*)d_in[25];
    const float* ff_w2  = (const float*)d_in[26];
    const float* ff_b2  = (const float*)d_in[27];
    const float* adaf_w = (const float*)d_in[28];
    const float* adaf_b = (const float*)d_in[29];
    const float* fin_w  = (const float*)d_in[30];
    const float* fin_b  = (const float*)d_in[31];
    float* outp = (float*)d_out;

    const int M = B_ * S_;               // 2048
    const size_t MN = (size_t)M * E_;    // 2 Mi floats
    float* ws      = (float*)d_ws;
    float* hbuf    = ws;                         // MN fp32 (residual stream)
    float* tbuf    = ws + MN;                    // MN fp32 (final-LN out)
    short* tbuf_bf = (short*)tbuf;               // bf16 view (LN outs)
    float* big     = ws + 2 * MN;                // 3*MN fp32 (qkv out)
    short* ff_bf   = (short*)big;                // 4*MN bf16 (ff1 out, aliases big)
    short* abuf_bf = (short*)(ws + 5 * MN);      // MN bf16 (attn out)
    short* wtbuf   = (short*)(ws + 5 * MN + MN / 2);  // up to 4*E*E bf16 (xposed weights)
    float* mods    = ws + 5 * MN + MN / 2 + MN;  // 4*B*6E
    float* adafm   = mods + 4 * B_ * 6 * E_;     // B*2E
    float* lamb    = adafm + B_ * 2 * E_;        // 4

    double li[4];
    for (int i = 0; i < 4; ++i) li[i] = 0.8 - 0.6 * exp(-0.3 * (i + 1));

    lam_k<<<1, 256, 0, stream>>>(lq1, lk1, lq2, lk2, lamb,
                                 (float)li[0], (float)li[1], (float)li[2], (float)li[3]);
    for (int i = 0; i < 4; ++i)
        small_gemm_k<<<(B_ * 6 * E_) / 256, 256, 0, stream>>>(
            emb, ada_w + (size_t)i * E_ * 6 * E_, ada_b + (size_t)i * 6 * E_,
            mods + (size_t)i * B_ * 6 * E_, 6 * E_);
    small_gemm_k<<<(B_ * 2 * E_) / 256, 256, 0, stream>>>(emb, adaf_w, adaf_b, adafm, 2 * E_);

    // l2e: t = snake(x @ w1 + b1) [bf16]; h = t @ w2t + b2 [fp32, MFMA]
    gemm_k<1, true><<<dim3(E_ / 64, M / 64), 256, 0, stream>>>(
        x, l2e_w1, l2e_b1, tbuf_bf, M, E_, 64, l2e_al, l2e_be);
    wcvt_k<<<dim3(E_ / 64, E_ / 64), 256, 0, stream>>>(l2e_w2, wtbuf, E_, E_);
    mgemm_k<64, 128, 1, 4, 0, false><<<dim3(E_ / 128, M / 64), 256, 0, stream>>>(
        tbuf_bf, wtbuf, l2e_b2, hbuf, M, E_, E_, nullptr, nullptr, nullptr, 0);

    for (int i = 0; i < 4; ++i) {
        const float* mi = mods + (size_t)i * B_ * 6 * E_;
        const float omli = 1.f - (float)li[i];

        ln_mod_k<true><<<M, 256, 0, stream>>>(hbuf, ln1_w + i * E_, ln1_b + i * E_,
                                              mi, mi + E_, 6 * E_, 1e-5f, tbuf_bf);
        wcvt_k<<<dim3(3 * E_ / 64, E_ / 64), 256, 0, stream>>>(
            qkv_w + (size_t)i * E_ * 3 * E_, wtbuf, E_, 3 * E_);
        mgemm_k<128, 128, 2, 2, 0, false><<<dim3(3 * E_ / 128, M / 128), 256, 0, stream>>>(
            tbuf_bf, wtbuf, nullptr, big, M, 3 * E_, E_, nullptr, nullptr, nullptr, 0);
        rotary_k<<<(B_ * S_ * 16 * 16) / 256, 256, 0, stream>>>(big);
        fattn_k<<<dim3(16, 8, B_), 256, 0, stream>>>(
            big, lamb + i, aln_w + i * 128, aln_b + i * 128, abuf_bf, omli);
        wcvt_k<<<dim3(E_ / 64, E_ / 64), 256, 0, stream>>>(
            out_w + (size_t)i * E_ * E_, wtbuf, E_, E_);
        mgemm_k<64, 128, 1, 4, 2, false><<<dim3(E_ / 128, M / 64), 256, 0, stream>>>(
            abuf_bf, wtbuf, nullptr, hbuf, M, E_, E_, mi + 4 * E_, nullptr, hbuf, 6 * E_);

        ln_mod_k<true><<<M, 256, 0, stream>>>(hbuf, ln2_w + i * E_, ln2_b + i * E_,
                                              mi + 2 * E_, mi + 3 * E_, 6 * E_, 1e-5f, tbuf_bf);
        wcvt_k<<<dim3(4 * E_ / 64, E_ / 64), 256, 0, stream>>>(
            ff_w1 + (size_t)i * E_ * 4 * E_, wtbuf, E_, 4 * E_);
        mgemm_k<128, 128, 2, 2, 1, true><<<dim3(4 * E_ / 128, M / 128), 256, 0, stream>>>(
            tbuf_bf, wtbuf, ff_b1 + i * 4 * E_, ff_bf, M, 4 * E_, E_,
            ff_al + i * 4 * E_, ff_be + i * 4 * E_, nullptr, 0);
        wcvt_k<<<dim3(E_ / 64, 4 * E_ / 64), 256, 0, stream>>>(
            ff_w2 + (size_t)i * 4 * E_ * E_, wtbuf, 4 * E_, E_);
        mgemm_k<64, 128, 1, 4, 2, false><<<dim3(E_ / 128, M / 64), 256, 0, stream>>>(
            ff_bf, wtbuf, ff_b2 + i * E_, hbuf, M, E_, 4 * E_, mi + 5 * E_, nullptr, hbuf, 6 * E_);
    }

    ln_mod_k<false><<<M, 256, 0, stream>>>(hbuf, nullptr, nullptr, adafm, adafm + E_,
                                           2 * E_, 1e-6f, tbuf);
    gemm_k<0, false><<<dim3(1, M / 64), 256, 0, stream>>>(
        tbuf, fin_w, fin_b, outp, M, 64, E_, nullptr, nullptr);
}